// Round 11
// baseline (75.311 us; speedup 1.0000x reference)
//
#include <hip/hip_runtime.h>

// AdaptivePatcher: B=32 seqs of S=16384 int32 tokens (0..7).
// MIN_PS=1, MAX_PS=8, LOOKAHEAD=4, THRESH=1.2 bits, PAD=0.
//
// Math (verified rounds 2-8, absmax=0):
//  - hi[p] <=> distinct-count of (masked) 4-window >= 3
//  - is_start[j] = hi[j] || ((j - a(j)) % 8 == 0), a(j)=max(last hi < j, 0)
//  - size at start j = min(first d in [1,8) with hi[j+d], else 8, S-j)
//  - leading-run count of chunk [lo,lo+fl) with incoming anchor a:
//      ceil((lo+fl-a)/8) - ceil((lo-a)/8); internal count A is
//      anchor-independent (verified closed form, rounds 4-8).
//
// Round-11 = round-9/10 resubmit (two infra timeouts, never ran).
// Discriminating experiment — 2-kernel split, ZERO atomics/spins.
// K1: hi bits (packed) + per-chunk summary {lastHi, firstHiLocal, A}.
// K2: anchor/base from summaries via plain loads (kernel boundary = ordering),
//     rank-order coalesced emit, tail fill; block 0 computes nout+cu from
//     the 256 summaries directly. If the round-8 fused kernel's residual was
//     atomic/spin overhead, dur drops to ~60-64; if dur stays ~72 the
//     residual is the harness's 256MiB 0xAA ws re-poison (42us @ 80% HBM
//     peak, top dispatch every round) + fixed replay overhead = floor.

#define S_LEN 16384
#define BATCH 32
#define NCH 8
#define CHUNK 2048
#define NTH 1024
#define PPT 2
#define NWV (NTH / 64)          // 16 waves
#define WPS 512                 // hi words per seq
#define WPC 64                  // hi words per chunk
#define MAX_PS 8

// ---------------- K1: hi bits + per-chunk summaries ----------------
__global__ __launch_bounds__(NTH)
void k1_hi(const int* __restrict__ tokens,
           unsigned* __restrict__ hiBits,   // [B, 512]
           int4* __restrict__ summ)         // [B*8]: {lastHi, fhl, A, 0}
{
    const int blk = blockIdx.x;
    const int b = blk >> 3, c = blk & 7;
    const int t = threadIdx.x;
    const int lane = t & 63, wv = t >> 6;
    const int cs = c * CHUNK;
    const int pl = t * PPT;
    const int p = cs + pl;
    const int* __restrict__ seq = tokens + (size_t)b * S_LEN;

    __shared__ unsigned char bs[NTH];
    __shared__ int partMax[NWV], partSum[NWV], red[2 * NWV];

    // load 6 tokens (2 own + 4 lookahead), int2-aligned
    int v[6];
    if (p + 5 < S_LEN) {
        int2 a2 = *(const int2*)(seq + p);
        int2 b2 = *(const int2*)(seq + p + 2);
        int2 c2 = *(const int2*)(seq + p + 4);
        v[0]=a2.x; v[1]=a2.y; v[2]=b2.x; v[3]=b2.y; v[4]=c2.x; v[5]=c2.y;
    } else {
#pragma unroll
        for (int i = 0; i < 6; ++i) v[i] = (p + i < S_LEN) ? seq[p + i] : 0;
    }

    unsigned hb = 0;
    int llh = -1, ffh = S_LEN;
#pragma unroll
    for (int k = 0; k < PPT; ++k) {
        int j = p + k;
        int nv = min(4, S_LEN - j);
        unsigned m = 0;
#pragma unroll
        for (int i = 0; i < 4; ++i) if (i < nv) m |= 1u << (v[k + i] & 31);
        int h = (__popc(m) >= 3) ? 1 : 0;
        hb |= (unsigned)h << k;
        if (h) { llh = j; if (ffh == S_LEN) ffh = j; }
    }
    bs[t] = (unsigned char)hb;

    // wave reductions (max llh, min ffh) + exclusive prefix-max of llh
    int mx = llh, mn = ffh;
#pragma unroll
    for (int d = 32; d >= 1; d >>= 1) {
        mx = max(mx, __shfl_down(mx, d));
        mn = min(mn, __shfl_down(mn, d));
    }
    if (lane == 0) { red[wv] = mx; red[NWV + wv] = mn; }
    int incl = llh;
#pragma unroll
    for (int d = 1; d < 64; d <<= 1) {
        int u = __shfl_up(incl, d);
        if (lane >= d) incl = max(incl, u);
    }
    if (lane == 63) partMax[wv] = incl;
    __syncthreads();                                    // (1)

    if (t < WPC) {
        unsigned w = 0;
#pragma unroll
        for (int i = 0; i < 16; ++i) w |= (unsigned)bs[16 * t + i] << (2 * i);
        hiBits[b * WPS + c * WPC + t] = w;
    }

    int runx = __shfl_up(incl, 1);
    if (lane == 0) runx = -1;
    for (int w = 0; w < wv; ++w) runx = max(runx, partMax[w]);

    // internal start count A (anchor-independent)
    int run = runx, ci = 0;
#pragma unroll
    for (int k = 0; k < PPT; ++k) {
        int j = p + k;
        int h = (hb >> k) & 1;
        int is = h | ((run >= 0) & (((j - run) & 7) == 0));
        ci += is;
        if (h) run = j;
    }
    int s = ci;
#pragma unroll
    for (int d = 32; d >= 1; d >>= 1) s += __shfl_down(s, d);
    if (lane == 0) partSum[wv] = s;
    __syncthreads();                                    // (2)

    if (t == 0) {
        int lastHi = red[0], fh = red[NWV];
        for (int w = 1; w < NWV; ++w) {
            lastHi = max(lastHi, red[w]);
            fh = min(fh, red[NWV + w]);
        }
        int fhl = min(fh - cs, CHUNK);
        int A = 0;
        for (int w = 0; w < NWV; ++w) A += partSum[w];
        summ[blk] = make_int4(lastHi, fhl, A, 0);
    }
}

// ---------------- K2: ranks + emit + tail + nout/cu ----------------
__global__ __launch_bounds__(NTH)
void k2_emit(const int* __restrict__ tokens,
             const unsigned* __restrict__ hiBits,
             const int4* __restrict__ summ,
             int* __restrict__ patches,     // [B, S, 8]
             int* __restrict__ offsets,     // [B, S]
             int* __restrict__ nout,        // [B]
             int* __restrict__ cu)          // [B+1]
{
    const int blk = blockIdx.x;
    const int b = blk >> 3, c = blk & 7;
    const int t = threadIdx.x;
    const int lane = t & 63, wv = t >> 6;
    const int cs = c * CHUNK;
    const int pl = t * PPT;
    const int p = cs + pl;
    const int* __restrict__ seq = tokens + (size_t)b * S_LEN;
    int* __restrict__ pat = patches + (size_t)b * S_LEN * MAX_PS;
    int* __restrict__ off = offsets + (size_t)b * S_LEN;

    __shared__ int tok_s[CHUNK + 8];
    __shared__ unsigned short rs_s[CHUNK];
    __shared__ unsigned hw[WPC + 1];
    __shared__ int4 sum_s[NCH];
    __shared__ int partMax[NWV], partSum[NWV];
    __shared__ int anch_s, base_s, ctot_s, ntot_s;

    // ---- loads ----
    {
        int2 a2 = *(const int2*)(seq + p);      // p+1 <= 16383 always
        *(int2*)&tok_s[pl] = a2;
    }
    if (t < 8) {
        int j2 = cs + CHUNK + t;
        tok_s[CHUNK + t] = (j2 < S_LEN) ? seq[j2] : 0;
    }
    if (t < WPC) hw[t] = hiBits[b * WPS + c * WPC + t];
    if (t == WPC) hw[WPC] = (c < NCH - 1) ? hiBits[b * WPS + (c + 1) * WPC] : 0u;
    if (t < NCH) sum_s[t] = summ[b * NCH + t];
    __syncthreads();                                    // (1)

    // own hi bits from packed words
    unsigned hb = (hw[t >> 4] >> (2 * (t & 15))) & 3u;
    int llh = -1;
    if (hb & 1u) llh = p;
    if (hb & 2u) llh = p + 1;

    // exclusive prefix-max scan of llh
    int incl = llh;
#pragma unroll
    for (int d = 1; d < 64; d <<= 1) {
        int u = __shfl_up(incl, d);
        if (lane >= d) incl = max(incl, u);
    }
    if (lane == 63) partMax[wv] = incl;

    // t0: anchor/base/ntot from the 8 summaries (closed form, verified)
    if (t == 0) {
        int anchor = -1, acc = 0;
        for (int cp = 0; cp < NCH; ++cp) {
            if (cp == c) { anch_s = anchor; base_s = acc; }
            int lh = sum_s[cp].x, fl = sum_s[cp].y, A = sum_s[cp].z;
            int lo = cp * CHUNK, hi2 = lo + fl;
            int a = max(anchor, 0);
            acc += ((hi2 - a + 7) >> 3) - ((lo - a + 7) >> 3) + A;
            if (lh >= 0) anchor = lh;
        }
        ntot_s = acc;
    }
    __syncthreads();                                    // (2)

    int runx = __shfl_up(incl, 1);
    if (lane == 0) runx = -1;
    for (int w = 0; w < wv; ++w) runx = max(runx, partMax[w]);

    // flags + local counts
    int run = max(runx, anch_s);
    unsigned fb = 0;
    int cl = 0;
#pragma unroll
    for (int k = 0; k < PPT; ++k) {
        int j = p + k;
        int h = (hb >> k) & 1;
        int a = max(run, 0);
        int is = h | (((j - a) & 7) == 0);
        fb |= (unsigned)is << k;
        cl += is;
        if (h) run = j;
    }
    int sincl = cl;
#pragma unroll
    for (int d = 1; d < 64; d <<= 1) {
        int u = __shfl_up(sincl, d);
        if (lane >= d) sincl += u;
    }
    if (lane == 63) partSum[wv] = sincl;
    __syncthreads();                                    // (3)
    int sexcl = __shfl_up(sincl, 1);
    if (lane == 0) sexcl = 0;
    int lr = sexcl;                                     // local rank
    for (int w = 0; w < wv; ++w) lr += partSum[w];
    if (t == 0) {
        int ctot = 0;
        for (int w = 0; w < NWV; ++w) ctot += partSum[w];
        ctot_s = ctot;
    }

    // scatter local rank -> local start pos
    {
        int q = lr;
#pragma unroll
        for (int k = 0; k < PPT; ++k) {
            if ((fb >> k) & 1u) rs_s[q++] = (unsigned short)(pl + k);
        }
    }
    __syncthreads();                                    // (4)

    // ---- rank-order emit (dense coalesced stores) ----
    const int base = base_s, ctot = ctot_s;
    for (int r2 = t; r2 < ctot; r2 += NTH) {
        int pos = rs_s[r2];
        int j = cs + pos;
        int size = 8;
#pragma unroll
        for (int d = 1; d <= 7; ++d) {
            int bb = pos + d;
            if ((hw[bb >> 5] >> (bb & 31)) & 1u) { size = d; break; }
        }
        size = min(size, S_LEN - j);
        int vals[8];
#pragma unroll
        for (int q = 0; q < 8; ++q) vals[q] = (q < size) ? tok_s[pos + q] : 0;
        off[base + r2] = j;
        int4* dst = (int4*)(pat + (size_t)(base + r2) * MAX_PS);
        dst[0] = make_int4(vals[0], vals[1], vals[2], vals[3]);
        dst[1] = make_int4(vals[4], vals[5], vals[6], vals[7]);
    }

    // ---- tail fill (block c==7 of each sequence) ----
    if (c == NCH - 1) {
        const int4 z = make_int4(0, 0, 0, 0);
        for (int r2 = ntot_s + t; r2 < S_LEN; r2 += NTH) {
            off[r2] = -1;
            int4* dst = (int4*)(pat + (size_t)r2 * MAX_PS);
            dst[0] = z;
            dst[1] = z;
        }
    }

    // ---- nout + cu_seqlens: block 0, wave 0 (plain loads, no waits) ----
    if (blk == 0 && wv == 0) {
        int ntl = 0;
        if (lane < BATCH) {
            int anchor = -1;
            for (int cp = 0; cp < NCH; ++cp) {
                int4 sv = summ[lane * NCH + cp];
                int lo = cp * CHUNK, hi2 = lo + sv.y;
                int a = max(anchor, 0);
                ntl += ((hi2 - a + 7) >> 3) - ((lo - a + 7) >> 3) + sv.z;
                if (sv.x >= 0) anchor = sv.x;
            }
            nout[lane] = ntl;
        }
        int sc2 = ntl;
#pragma unroll
        for (int d = 1; d < 32; d <<= 1) {
            int u = __shfl_up(sc2, d);
            if (lane >= d) sc2 += u;
        }
        if (lane < BATCH) cu[lane + 1] = sc2;
        if (lane == 0) cu[0] = 0;
    }
}

extern "C" void kernel_launch(void* const* d_in, const int* in_sizes, int n_in,
                              void* d_out, int out_size, void* d_ws, size_t ws_size,
                              hipStream_t stream)
{
    const int* tokens = (const int*)d_in[0];
    int* out = (int*)d_out;
    // Output layout (int32, return order):
    //   patches [32,16384,8] -> 4,194,304 ; offsets [32,16384] -> 524,288 ;
    //   n [32] ; cu_seqlens [33]
    int* patches = out;
    int* offsets = patches + (size_t)BATCH * S_LEN * MAX_PS;
    int* nout    = offsets + (size_t)BATCH * S_LEN;
    int* cu      = nout + BATCH;

    // workspace: hiBits 64KB, then summaries 4KB (16B-aligned)
    unsigned* hiBits = (unsigned*)d_ws;
    int4* summ = (int4*)((char*)d_ws + (size_t)BATCH * WPS * sizeof(unsigned));

    k1_hi  <<<dim3(BATCH * NCH), dim3(NTH), 0, stream>>>(tokens, hiBits, summ);
    k2_emit<<<dim3(BATCH * NCH), dim3(NTH), 0, stream>>>(tokens, hiBits, summ,
                                                         patches, offsets, nout, cu);
}